// Round 15
// baseline (139.386 us; speedup 1.0000x reference)
//
#include <hip/hip_runtime.h>

typedef short bf16x8 __attribute__((ext_vector_type(8)));
typedef float f32x4 __attribute__((ext_vector_type(4)));
typedef unsigned int u32x4 __attribute__((ext_vector_type(4)));
typedef unsigned short u16x4 __attribute__((ext_vector_type(4)));

__device__ __forceinline__ unsigned short f2bf(float f) {
  unsigned u = __builtin_bit_cast(unsigned, f);
  u = (u + 0x7FFFu + ((u >> 16) & 1u)) >> 16;   // RNE bf16
  return (unsigned short)u;
}

// ---------------- Kernel P: partial pooling sums + x -> bf16 cast ----------
__global__ __launch_bounds__(256) void k_pool_cvt(const float* __restrict__ x,
                                                  unsigned short* __restrict__ xb,
                                                  float* __restrict__ pp) {
  const int slice = blockIdx.x;       // 0..15
  const int b = blockIdx.y;           // 0..31
  const int t = threadIdx.x;
  const int c4 = (t & 31) * 4;
  const int seg = t >> 5;
  const size_t base = ((size_t)b * 4096 + slice * 256 + seg * 32) * 128;
  const float* xp = x + base;
  unsigned short* xbp = xb + base;
  f32x4 s = {0.f, 0.f, 0.f, 0.f};
  for (int p = 0; p < 32; ++p) {
    f32x4 v = *(const f32x4*)(xp + p * 128 + c4);
    s += v;
    u16x4 h;
    h.x = f2bf(v.x); h.y = f2bf(v.y); h.z = f2bf(v.z); h.w = f2bf(v.w);
    *(u16x4*)(xbp + p * 128 + c4) = h;
  }
  __shared__ f32x4 red[256];
  red[t] = s;
  __syncthreads();
  if (t < 32) {
    f32x4 tot = red[t];
#pragma unroll
    for (int g = 1; g < 8; ++g) tot += red[g * 32 + t];
    *(f32x4*)(pp + (size_t)(b * 16 + slice) * 128 + t * 4) = tot;
  }
}

// ---------------- Kernel R: finish pool, attention softmax, fused BN bias --
__global__ __launch_bounds__(128) void k_route(const float* __restrict__ pp,
    const float* __restrict__ redk, const float* __restrict__ attk,
    const float* __restrict__ bias, const float* __restrict__ bns,
    const float* __restrict__ bnb, const float* __restrict__ bnm,
    const float* __restrict__ bnv,
    float* __restrict__ att_ws, float* __restrict__ beta_ws,
    float* __restrict__ alpha_ws) {
  const int b = blockIdx.x, t = threadIdx.x;
  __shared__ float pool[128];
  __shared__ float att[4];
  {
    float s = 0.f;
    for (int i = 0; i < 16; ++i) s += pp[(size_t)(b * 16 + i) * 128 + t];
    pool[t] = s * (1.f / 4096.f);
  }
  __syncthreads();
  if (t == 0) {
    float pr[4];
    for (int r = 0; r < 4; ++r) {
      float s = 0.f;
      for (int c = 0; c < 128; ++c) s += pool[c] * redk[c * 4 + r];
      pr[r] = fmaxf(s, 0.f);
    }
    float lgt[4]; float mx = -1e30f;
    for (int k = 0; k < 4; ++k) {
      float s = 0.f;
      for (int r = 0; r < 4; ++r) s += pr[r] * attk[r * 4 + k];
      lgt[k] = s * (1.f / 30.f);
      mx = fmaxf(mx, lgt[k]);
    }
    float den = 0.f;
    for (int k = 0; k < 4; ++k) { lgt[k] = expf(lgt[k] - mx); den += lgt[k]; }
    for (int k = 0; k < 4; ++k) { att[k] = lgt[k] / den; att_ws[b * 4 + k] = att[k]; }
  }
  __syncthreads();
  {
    float bm = 0.f;
    for (int k = 0; k < 4; ++k) bm += att[k] * bias[k * 128 + t];
    const float inv = bns[t] * rsqrtf(bnv[t] + 1e-5f);
    beta_ws[b * 128 + t] = (bm - bnm[t]) * inv + bnb[t];
    alpha_ws[t] = inv;
  }
}

// ---------------- Kernel W: mix experts, ck read ONCE; dw-MAJOR slab order -
// Grid 144 = (tap 9) x (c-quarter 4) x (f-quarter 4). Block stages the 4
// experts' [32c x 32f] chunk in LDS, mixes all 32 samples in-register.
// Slab contract: w_ws[b][ h*9 + dw*3 + dh ] 16KB slabs (dw-major so k_conv
// can hoist dw-dependent A-bases); chunk (f,o) at f*8+(o^(f&7)).
__global__ __launch_bounds__(256) void k_mixw(const float* __restrict__ ck,
                                              const float* __restrict__ att_ws,
                                              unsigned short* __restrict__ w_ws) {
  const int bx = blockIdx.x;
  const int tap = bx >> 4;        // 0..8 (= dh*3+dw in ck layout)
  const int cq = (bx >> 2) & 3;   // 32-ch quarter
  const int fq = bx & 3;          // 32-f quarter
  const int t = threadIdx.x;
  __shared__ float cw[4][32][32];   // [k][c][f]
  __shared__ float attl[128];
  if (t < 128) attl[t] = att_ws[t];
  {
    const int k = t >> 6, c = (t & 63) >> 1, f0 = (t & 1) * 16;
    const float* src = ck + ((size_t)(k * 9 + tap) * 128 + cq * 32 + c) * 128
                          + fq * 32 + f0;
    *(f32x4*)&cw[k][c][f0]      = *(const f32x4*)(src);
    *(f32x4*)&cw[k][c][f0 + 4]  = *(const f32x4*)(src + 4);
    *(f32x4*)&cw[k][c][f0 + 8]  = *(const f32x4*)(src + 8);
    *(f32x4*)&cw[k][c][f0 + 12] = *(const f32x4*)(src + 12);
  }
  __syncthreads();
  const int f = t & 31, o = (t >> 5) & 3, sh = t >> 7;
  const int fp = fq * 32 + f;
  const int h = cq >> 1;
  const int oslab = (cq & 1) * 4 + o;
  const int chunk = fp * 8 + (oslab ^ (fp & 7));
  const int slab = h * 9 + (tap % 3) * 3 + tap / 3;   // dw-major order
  float wv[4][8];
#pragma unroll
  for (int k = 0; k < 4; ++k)
#pragma unroll
    for (int j = 0; j < 8; ++j) wv[k][j] = cw[k][o * 8 + j][f];
#pragma unroll
  for (int bs = 0; bs < 16; ++bs) {
    const int b = sh * 16 + bs;
    const float a0 = attl[b * 4 + 0], a1 = attl[b * 4 + 1];
    const float a2 = attl[b * 4 + 2], a3 = attl[b * 4 + 3];
    bf16x8 ov;
#pragma unroll
    for (int j = 0; j < 8; ++j) {
      const float v = a0 * wv[0][j] + a1 * wv[1][j] + a2 * wv[2][j] + a3 * wv[3][j];
      ov[j] = (short)f2bf(v);
    }
    *(bf16x8*)(w_ws + (size_t)b * 147456 + (size_t)slab * 8192
               + (size_t)chunk * 8) = ov;
  }
}

// ---------------- Kernel C: 3x3 conv, dw-major slabs, hoisted bases --------
// Round-11 geometry+schedule (best verified 43.4 us): 512 blocks, 512 thr =
// 8 waves (4 wm x 2 wn), wave tile 64 px x 64 f, 18 slabs, LDS 80 KB
// (xt 48 + 2 x 16 w) -> 2 blocks/CU (16 waves).
// Slabs are dw-major (h, dw, dh): dw changes once per 3 slabs, so the
// dw-dependent per-lane A-bases hoist to the outer (rolled) g-loop — VALU
// per slab drops ~3-4x WITHOUT unrolling the slab loop (r14's unroll blew
// I-cache). Loads stay exec-predicated (ternary on load, clamped addr) —
// r10/r11-proven conflict-free. Single publish barrier per slab.
__device__ __forceinline__ void stage_w16(char* dst, const unsigned short* src, int t) {
#pragma unroll
  for (int j = 0; j < 2; ++j) {
    const int i = t + j * 512;            // 16B chunk, 1024 total
    __builtin_amdgcn_global_load_lds(
        (const __attribute__((address_space(1))) void*)(src + (size_t)i * 8),
        (__attribute__((address_space(3))) void*)(dst + i * 16), 16, 0, 0);
  }
}

__device__ __forceinline__ void stage_x_half(char* xt, const unsigned short* xbp,
                                             int r0, int h, int t) {
  const int pix = t >> 3;                             // 0..63
  const int oct = (t & 7) ^ ((t >> 3) & 7);           // pre-swizzled source oct
#pragma unroll
  for (int j = 0; j < 6; ++j) {
    const int rr = r0 - 1 + j;
    char* dst = xt + j * 8192 + t * 16;               // linear LDS dest
    if ((unsigned)rr < 64u) {
      __builtin_amdgcn_global_load_lds(
          (const __attribute__((address_space(1))) void*)
              (xbp + ((size_t)(rr * 64 + pix)) * 128 + h * 64 + oct * 8),
          (__attribute__((address_space(3))) void*)dst, 16, 0, 0);
    } else {
      *(u32x4*)dst = (u32x4){0, 0, 0, 0};             // zero padding row
    }
  }
}

__global__ __launch_bounds__(512, 4) void k_conv(const unsigned short* __restrict__ xb,
                                                 const unsigned short* __restrict__ w_ws,
                                                 const float* __restrict__ alpha_ws,
                                                 const float* __restrict__ beta_ws,
                                                 float* __restrict__ out) {
  extern __shared__ char lds[];           // 81920 B
  char* xt = lds;                         // 49152 B
  char* wlds = lds + 49152;               // 2 x 16384 B

  const int orig = blockIdx.x;
  const int wg = (orig & 7) * 64 + (orig >> 3);   // XCD-chunked, bijective
  const int b = wg >> 4;
  const int tile = wg & 15;
  const int t = threadIdx.x;
  const int lane = t & 63, wid = t >> 6;
  const int wm = wid >> 1, wn = wid & 1;          // wave -> (row, f-half)
  const int lr = lane & 15, lg = lane >> 4;
  const int r0 = tile * 4;

  const unsigned short* xbp = xb + (size_t)b * 4096 * 128;
  const unsigned short* wsrc = w_ws + (size_t)b * 18 * 8192;

  f32x4 acc[4][4] = {};
  const bf16x8 zero = {};

  // B-bases: dw-independent, hoisted for the whole kernel.
  int bbase[4];
#pragma unroll
  for (int nf = 0; nf < 4; ++nf) {
    const int f = wn * 64 + nf * 16 + lr;
    bbase[nf] = (f * 128 + lg * 16) ^ ((f & 7) << 4);
  }

  // Prologue: x half 0 + slab 0; full drain (pad ds_writes need lgkmcnt).
  stage_x_half(xt, xbp, r0, 0, t);
  stage_w16(wlds, wsrc, t);
  asm volatile("s_waitcnt vmcnt(0) lgkmcnt(0)" ::: "memory");
  __builtin_amdgcn_s_barrier();
  asm volatile("" ::: "memory");

  for (int g = 0; g < 6; ++g) {           // g = h*3 + dw-index (rolled)
    // A-bases for this dw (computed once per 3 slabs).
    const int dw = g - (g >= 3 ? 3 : 0) - 1;      // g%3 - 1
    int abase[4]; bool aval[4];
#pragma unroll
    for (int mf = 0; mf < 4; ++mf) {
      const int col = mf * 16 + lr + dw;          // -1..64
      aval[mf] = (unsigned)col < 64u;
      const int cc = col & 63;                    // clamped: always valid addr
      abase[mf] = (cc * 128 + lg * 16) ^ ((cc & 7) << 4);
    }

#pragma unroll
    for (int dh = 0; dh < 3; ++dh) {              // slab = g*3 + dh
      const int s = g * 3 + dh;
      char* cb = wlds + ((s & 1) << 14);
      // Stage slab s+1 into the buffer freed by the previous end barrier.
      if (s < 17) stage_w16(wlds + (((s + 1) & 1) << 14),
                            wsrc + (size_t)(s + 1) * 8192, t);

      const int jr = (wm + dh) * 8192;            // wave-uniform row offset
#pragma unroll
      for (int kc = 0; kc < 2; ++kc) {
        const int kx = kc << 6;                   // XOR, not add (bit 6)
        bf16x8 afr[4], bfr[4];
#pragma unroll
        for (int mf = 0; mf < 4; ++mf)
          afr[mf] = aval[mf] ? *(const bf16x8*)(xt + (jr + (abase[mf] ^ kx)))
                             : zero;
#pragma unroll
        for (int nf = 0; nf < 4; ++nf)
          bfr[nf] = *(const bf16x8*)(cb + (bbase[nf] ^ kx));
        __builtin_amdgcn_s_setprio(1);
#pragma unroll
        for (int mf = 0; mf < 4; ++mf)
#pragma unroll
          for (int nf = 0; nf < 4; ++nf)
            acc[mf][nf] = __builtin_amdgcn_mfma_f32_16x16x32_bf16(
                afr[mf], bfr[nf], acc[mf][nf], 0, 0, 0);
        __builtin_amdgcn_s_setprio(0);
      }
      asm volatile("" ::: "memory");   // reads complete before barrier region

      if (s == 8) {
        // All waves done reading xt half 0 -> restage x half 1, drain all.
        __builtin_amdgcn_s_barrier();
        stage_x_half(xt, xbp, r0, 1, t);
        asm volatile("s_waitcnt vmcnt(0) lgkmcnt(0)" ::: "memory");
        __builtin_amdgcn_s_barrier();
        asm volatile("" ::: "memory");
      } else if (s < 17) {
        // Slab s+1 landed (covered by the full MFMA phase); single barrier.
        asm volatile("s_waitcnt vmcnt(0)" ::: "memory");
        __builtin_amdgcn_s_barrier();
        asm volatile("" ::: "memory");
      }
    }
  }

  // Fused epilogue: relu(acc * inv + beta)
  float af[4], bt[4];
#pragma unroll
  for (int nf = 0; nf < 4; ++nf) {
    const int f = wn * 64 + nf * 16 + lr;
    af[nf] = alpha_ws[f];
    bt[nf] = beta_ws[b * 128 + f];
  }
  float* op = out + (size_t)b * 4096 * 128;
  const int row = r0 + wm;
#pragma unroll
  for (int mf = 0; mf < 4; ++mf) {
#pragma unroll
    for (int r = 0; r < 4; ++r) {
      const int col = mf * 16 + lg * 4 + r;       // C/D: row-in-frag = lg*4+reg
#pragma unroll
      for (int nf = 0; nf < 4; ++nf) {
        const int f = wn * 64 + nf * 16 + lr;     // C/D: col-in-frag = lane&15
        const float v = acc[mf][nf][r] * af[nf] + bt[nf];
        op[(size_t)(row * 64 + col) * 128 + f] = fmaxf(v, 0.f);
      }
    }
  }
}

extern "C" void kernel_launch(void* const* d_in, const int* in_sizes, int n_in,
                              void* d_out, int out_size, void* d_ws, size_t ws_size,
                              hipStream_t stream) {
  const float* x    = (const float*)d_in[0];
  const float* redk = (const float*)d_in[1];
  const float* attk = (const float*)d_in[2];
  const float* ck   = (const float*)d_in[3];
  const float* bias = (const float*)d_in[4];
  const float* bns  = (const float*)d_in[5];
  const float* bnbb = (const float*)d_in[6];
  const float* bnm  = (const float*)d_in[7];
  const float* bnv  = (const float*)d_in[8];
  float* out = (float*)d_out;

  char* ws = (char*)d_ws;
  unsigned short* xb   = (unsigned short*)ws;                  // 33,554,432 B
  unsigned short* w_ws = (unsigned short*)(ws + 33554432);     //  9,437,184 B
  float* pp       = (float*)(ws + 42991616);                   //    262,144 B
  float* att_ws   = (float*)(ws + 43253760);
  float* beta_ws  = (float*)(ws + 43254272);
  float* alpha_ws = (float*)(ws + 43270656);

  k_pool_cvt<<<dim3(16, 32), 256, 0, stream>>>(x, xb, pp);
  k_route<<<32, 128, 0, stream>>>(pp, redk, attk, bias, bns, bnbb, bnm, bnv,
                                  att_ws, beta_ws, alpha_ws);
  k_mixw<<<144, 256, 0, stream>>>(ck, att_ws, w_ws);
  k_conv<<<512, 512, 81920, stream>>>(xb, w_ws, alpha_ws, beta_ws, out);
}

// Round 16
// 75.400 us; speedup vs baseline: 1.8486x; 1.8486x over previous
//
#include <hip/hip_runtime.h>

typedef short bf16x8 __attribute__((ext_vector_type(8)));
typedef float f32x4 __attribute__((ext_vector_type(4)));
typedef unsigned int u32x4 __attribute__((ext_vector_type(4)));
typedef unsigned short u16x4 __attribute__((ext_vector_type(4)));

__device__ __forceinline__ unsigned short f2bf(float f) {
  unsigned u = __builtin_bit_cast(unsigned, f);
  u = (u + 0x7FFFu + ((u >> 16) & 1u)) >> 16;   // RNE bf16
  return (unsigned short)u;
}

// ---------------- Kernel P: partial pooling sums + x -> bf16 cast ----------
__global__ __launch_bounds__(256) void k_pool_cvt(const float* __restrict__ x,
                                                  unsigned short* __restrict__ xb,
                                                  float* __restrict__ pp) {
  const int slice = blockIdx.x;       // 0..15
  const int b = blockIdx.y;           // 0..31
  const int t = threadIdx.x;
  const int c4 = (t & 31) * 4;
  const int seg = t >> 5;
  const size_t base = ((size_t)b * 4096 + slice * 256 + seg * 32) * 128;
  const float* xp = x + base;
  unsigned short* xbp = xb + base;
  f32x4 s = {0.f, 0.f, 0.f, 0.f};
  for (int p = 0; p < 32; ++p) {
    f32x4 v = *(const f32x4*)(xp + p * 128 + c4);
    s += v;
    u16x4 h;
    h.x = f2bf(v.x); h.y = f2bf(v.y); h.z = f2bf(v.z); h.w = f2bf(v.w);
    *(u16x4*)(xbp + p * 128 + c4) = h;
  }
  __shared__ f32x4 red[256];
  red[t] = s;
  __syncthreads();
  if (t < 32) {
    f32x4 tot = red[t];
#pragma unroll
    for (int g = 1; g < 8; ++g) tot += red[g * 32 + t];
    *(f32x4*)(pp + (size_t)(b * 16 + slice) * 128 + t * 4) = tot;
  }
}

// ---------------- Kernel R: finish pool, attention softmax, fused BN bias --
__global__ __launch_bounds__(128) void k_route(const float* __restrict__ pp,
    const float* __restrict__ redk, const float* __restrict__ attk,
    const float* __restrict__ bias, const float* __restrict__ bns,
    const float* __restrict__ bnb, const float* __restrict__ bnm,
    const float* __restrict__ bnv,
    float* __restrict__ att_ws, float* __restrict__ beta_ws,
    float* __restrict__ alpha_ws) {
  const int b = blockIdx.x, t = threadIdx.x;
  __shared__ float pool[128];
  __shared__ float att[4];
  {
    float s = 0.f;
    for (int i = 0; i < 16; ++i) s += pp[(size_t)(b * 16 + i) * 128 + t];
    pool[t] = s * (1.f / 4096.f);
  }
  __syncthreads();
  if (t == 0) {
    float pr[4];
    for (int r = 0; r < 4; ++r) {
      float s = 0.f;
      for (int c = 0; c < 128; ++c) s += pool[c] * redk[c * 4 + r];
      pr[r] = fmaxf(s, 0.f);
    }
    float lgt[4]; float mx = -1e30f;
    for (int k = 0; k < 4; ++k) {
      float s = 0.f;
      for (int r = 0; r < 4; ++r) s += pr[r] * attk[r * 4 + k];
      lgt[k] = s * (1.f / 30.f);
      mx = fmaxf(mx, lgt[k]);
    }
    float den = 0.f;
    for (int k = 0; k < 4; ++k) { lgt[k] = expf(lgt[k] - mx); den += lgt[k]; }
    for (int k = 0; k < 4; ++k) { att[k] = lgt[k] / den; att_ws[b * 4 + k] = att[k]; }
  }
  __syncthreads();
  {
    float bm = 0.f;
    for (int k = 0; k < 4; ++k) bm += att[k] * bias[k * 128 + t];
    const float inv = bns[t] * rsqrtf(bnv[t] + 1e-5f);
    beta_ws[b * 128 + t] = (bm - bnm[t]) * inv + bnb[t];
    alpha_ws[t] = inv;
  }
}

// ---------------- Kernel W: mix experts, ck read ONCE (not per-sample) -----
// Grid 144 = (tap 9) x (c-quarter 4) x (f-quarter 4). Block stages the 4
// experts' [32c x 32f] chunk in LDS, then mixes all 32 samples in-register.
// Slab contract: w_ws[b][h*9+tap] 16KB slabs, chunk (f,o) at f*8+(o^(f&7)).
__global__ __launch_bounds__(256) void k_mixw(const float* __restrict__ ck,
                                              const float* __restrict__ att_ws,
                                              unsigned short* __restrict__ w_ws) {
  const int bx = blockIdx.x;
  const int tap = bx >> 4;        // 0..8
  const int cq = (bx >> 2) & 3;   // 32-ch quarter
  const int fq = bx & 3;          // 32-f quarter
  const int t = threadIdx.x;
  __shared__ float cw[4][32][32];   // [k][c][f]
  __shared__ float attl[128];
  if (t < 128) attl[t] = att_ws[t];
  {
    const int k = t >> 6, c = (t & 63) >> 1, f0 = (t & 1) * 16;
    const float* src = ck + ((size_t)(k * 9 + tap) * 128 + cq * 32 + c) * 128
                          + fq * 32 + f0;
    *(f32x4*)&cw[k][c][f0]      = *(const f32x4*)(src);
    *(f32x4*)&cw[k][c][f0 + 4]  = *(const f32x4*)(src + 4);
    *(f32x4*)&cw[k][c][f0 + 8]  = *(const f32x4*)(src + 8);
    *(f32x4*)&cw[k][c][f0 + 12] = *(const f32x4*)(src + 12);
  }
  __syncthreads();
  const int f = t & 31, o = (t >> 5) & 3, sh = t >> 7;
  const int fp = fq * 32 + f;
  const int h = cq >> 1;
  const int oslab = (cq & 1) * 4 + o;
  const int chunk = fp * 8 + (oslab ^ (fp & 7));
  float wv[4][8];
#pragma unroll
  for (int k = 0; k < 4; ++k)
#pragma unroll
    for (int j = 0; j < 8; ++j) wv[k][j] = cw[k][o * 8 + j][f];
#pragma unroll
  for (int bs = 0; bs < 16; ++bs) {
    const int b = sh * 16 + bs;
    const float a0 = attl[b * 4 + 0], a1 = attl[b * 4 + 1];
    const float a2 = attl[b * 4 + 2], a3 = attl[b * 4 + 3];
    bf16x8 ov;
#pragma unroll
    for (int j = 0; j < 8; ++j) {
      const float v = a0 * wv[0][j] + a1 * wv[1][j] + a2 * wv[2][j] + a3 * wv[3][j];
      ov[j] = (short)f2bf(v);
    }
    *(bf16x8*)(w_ws + (size_t)b * 147456 + (size_t)(h * 9 + tap) * 8192
               + (size_t)chunk * 8) = ov;
  }
}

// ---------------- Kernel C: 3x3 conv, single barrier per slab --------------
// Round-5 proven geometry: 512 blocks (32 samples x 16 row-quads), 512 thr =
// 8 waves (4 wm x 2 wn), wave tile 64 px x 64 f. 18 slabs (2 halves x 9 taps).
// LDS 80 KB: xt 48 KB + 2 x 16 KB weight slabs -> 2 blocks/CU (16 waves).
// Round-8 proven schedule: per iter — stage slab s+1 (buffer freed by prev
// end barrier), compute slab s (staging overlaps full MFMA phase), vmcnt(0),
// ONE barrier (publish). xt half-switch at s==8 keeps a double-barrier drain.
__device__ __forceinline__ void stage_w16(char* dst, const unsigned short* src, int t) {
#pragma unroll
  for (int j = 0; j < 2; ++j) {
    const int i = t + j * 512;            // 16B chunk, 1024 total
    __builtin_amdgcn_global_load_lds(
        (const __attribute__((address_space(1))) void*)(src + (size_t)i * 8),
        (__attribute__((address_space(3))) void*)(dst + i * 16), 16, 0, 0);
  }
}

__device__ __forceinline__ void stage_x_half(char* xt, const unsigned short* xbp,
                                             int r0, int h, int t) {
  const int pix = t >> 3;                             // 0..63
  const int oct = (t & 7) ^ ((t >> 3) & 7);           // pre-swizzled source oct
#pragma unroll
  for (int j = 0; j < 6; ++j) {
    const int rr = r0 - 1 + j;
    char* dst = xt + j * 8192 + t * 16;               // linear LDS dest
    if ((unsigned)rr < 64u) {
      __builtin_amdgcn_global_load_lds(
          (const __attribute__((address_space(1))) void*)
              (xbp + ((size_t)(rr * 64 + pix)) * 128 + h * 64 + oct * 8),
          (__attribute__((address_space(3))) void*)dst, 16, 0, 0);
    } else {
      *(u32x4*)dst = (u32x4){0, 0, 0, 0};             // zero padding row
    }
  }
}

__global__ __launch_bounds__(512, 4) void k_conv(const unsigned short* __restrict__ xb,
                                                 const unsigned short* __restrict__ w_ws,
                                                 const float* __restrict__ alpha_ws,
                                                 const float* __restrict__ beta_ws,
                                                 float* __restrict__ out) {
  extern __shared__ char lds[];           // 81920 B
  char* xt = lds;                         // 49152 B
  char* wlds = lds + 49152;               // 2 x 16384 B

  const int orig = blockIdx.x;
  const int wg = (orig & 7) * 64 + (orig >> 3);   // XCD-chunked, bijective
  const int b = wg >> 4;
  const int tile = wg & 15;
  const int t = threadIdx.x;
  const int lane = t & 63, wid = t >> 6;
  const int wm = wid >> 1, wn = wid & 1;          // wave -> (row, f-half)
  const int lr = lane & 15, lg = lane >> 4;
  const int r0 = tile * 4;

  const unsigned short* xbp = xb + (size_t)b * 4096 * 128;
  const unsigned short* wsrc = w_ws + (size_t)b * 18 * 8192;

  f32x4 acc[4][4] = {};
  const bf16x8 zero = {};

  // Prologue: x half 0 + slab 0; full drain (pad ds_writes need lgkmcnt).
  stage_x_half(xt, xbp, r0, 0, t);
  stage_w16(wlds, wsrc, t);
  asm volatile("s_waitcnt vmcnt(0) lgkmcnt(0)" ::: "memory");
  __builtin_amdgcn_s_barrier();
  asm volatile("" ::: "memory");

  for (int s = 0; s < 18; ++s) {
    const int tap = s % 9;
    char* cb = wlds + ((s & 1) << 14);
    // Stage slab s+1 into the buffer freed by the previous end barrier.
    if (s < 17) stage_w16(wlds + (((s + 1) & 1) << 14),
                          wsrc + (size_t)(s + 1) * 8192, t);

    const int dh = tap / 3 - 1, dw = tap % 3 - 1;
    const int jrow = wm + dh + 1;                 // 0..5 within xt
#pragma unroll
    for (int kc = 0; kc < 2; ++kc) {
      bf16x8 afr[4], bfr[4];
#pragma unroll
      for (int mf = 0; mf < 4; ++mf) {
        const int col = mf * 16 + lr + dw;        // -1..64
        const int a = ((jrow * 64 + col) * 128 + kc * 64 + lg * 16) ^ ((col & 7) << 4);
        afr[mf] = ((unsigned)col < 64u) ? *(const bf16x8*)(xt + a) : zero;
      }
#pragma unroll
      for (int nf = 0; nf < 4; ++nf) {
        const int f = wn * 64 + nf * 16 + lr;
        const int a = (f * 128 + kc * 64 + lg * 16) ^ ((f & 7) << 4);
        bfr[nf] = *(const bf16x8*)(cb + a);
      }
      __builtin_amdgcn_s_setprio(1);
#pragma unroll
      for (int mf = 0; mf < 4; ++mf)
#pragma unroll
        for (int nf = 0; nf < 4; ++nf)
          acc[mf][nf] = __builtin_amdgcn_mfma_f32_16x16x32_bf16(afr[mf], bfr[nf],
                                                                acc[mf][nf], 0, 0, 0);
      __builtin_amdgcn_s_setprio(0);
    }
    asm volatile("" ::: "memory");   // reads complete before barrier region

    if (s == 8) {
      // All waves done reading xt half 0 -> restage x half 1, drain all.
      __builtin_amdgcn_s_barrier();
      stage_x_half(xt, xbp, r0, 1, t);
      asm volatile("s_waitcnt vmcnt(0) lgkmcnt(0)" ::: "memory");
      __builtin_amdgcn_s_barrier();
      asm volatile("" ::: "memory");
    } else if (s < 17) {
      // Slab s+1 landed (covered by the full MFMA phase); single barrier.
      asm volatile("s_waitcnt vmcnt(0)" ::: "memory");
      __builtin_amdgcn_s_barrier();
      asm volatile("" ::: "memory");
    }
  }

  // Fused epilogue: relu(acc * inv + beta)
  float af[4], bt[4];
#pragma unroll
  for (int nf = 0; nf < 4; ++nf) {
    const int f = wn * 64 + nf * 16 + lr;
    af[nf] = alpha_ws[f];
    bt[nf] = beta_ws[b * 128 + f];
  }
  float* op = out + (size_t)b * 4096 * 128;
  const int row = r0 + wm;
#pragma unroll
  for (int mf = 0; mf < 4; ++mf) {
#pragma unroll
    for (int r = 0; r < 4; ++r) {
      const int col = mf * 16 + lg * 4 + r;       // C/D: row-in-frag = lg*4+reg
#pragma unroll
      for (int nf = 0; nf < 4; ++nf) {
        const int f = wn * 64 + nf * 16 + lr;     // C/D: col-in-frag = lane&15
        const float v = acc[mf][nf][r] * af[nf] + bt[nf];
        op[(size_t)(row * 64 + col) * 128 + f] = fmaxf(v, 0.f);
      }
    }
  }
}

extern "C" void kernel_launch(void* const* d_in, const int* in_sizes, int n_in,
                              void* d_out, int out_size, void* d_ws, size_t ws_size,
                              hipStream_t stream) {
  const float* x    = (const float*)d_in[0];
  const float* redk = (const float*)d_in[1];
  const float* attk = (const float*)d_in[2];
  const float* ck   = (const float*)d_in[3];
  const float* bias = (const float*)d_in[4];
  const float* bns  = (const float*)d_in[5];
  const float* bnbb = (const float*)d_in[6];
  const float* bnm  = (const float*)d_in[7];
  const float* bnv  = (const float*)d_in[8];
  float* out = (float*)d_out;

  char* ws = (char*)d_ws;
  unsigned short* xb   = (unsigned short*)ws;                  // 33,554,432 B
  unsigned short* w_ws = (unsigned short*)(ws + 33554432);     //  9,437,184 B
  float* pp       = (float*)(ws + 42991616);                   //    262,144 B
  float* att_ws   = (float*)(ws + 43253760);
  float* beta_ws  = (float*)(ws + 43254272);
  float* alpha_ws = (float*)(ws + 43270656);

  k_pool_cvt<<<dim3(16, 32), 256, 0, stream>>>(x, xb, pp);
  k_route<<<32, 128, 0, stream>>>(pp, redk, attk, bias, bns, bnbb, bnm, bnv,
                                  att_ws, beta_ws, alpha_ws);
  k_mixw<<<144, 256, 0, stream>>>(ck, att_ws, w_ws);
  k_conv<<<512, 512, 81920, stream>>>(xb, w_ws, alpha_ws, beta_ws, out);
}